// Round 3
// baseline (1834.066 us; speedup 1.0000x reference)
//
#include <hip/hip_runtime.h>
#include <math.h>

#define NN 50000
#define NF 63
#define NE 800000
#define NL 10000
#define NB 4
#define NLAY 5
#define BN (NB*NN)                 // 200000 rows
#define NTILES (BN/64)             // 3125
#define SCAN_NBLK ((NN+255)/256)   // 196
#define ATILES ((NN+63)/64)        // 782

using f32x4  = __attribute__((ext_vector_type(4))) float;
using bf16x8 = __attribute__((ext_vector_type(8))) __bf16;

__device__ __forceinline__ float sigm(float v){ return 1.f/(1.f + __expf(-v)); }

__device__ __forceinline__ ushort f2bf(float f){
    uint u = __builtin_bit_cast(uint, f);
    u += 0x7fffu + ((u >> 16) & 1u);
    return (ushort)(u >> 16);
}
__device__ __forceinline__ float bf_lo(uint v){ return __builtin_bit_cast(float, v << 16); }
__device__ __forceinline__ float bf_hi(uint v){ return __builtin_bit_cast(float, v & 0xffff0000u); }

__device__ __forceinline__ bf16x8 ldfrag(const ushort* p){
    uint4 v = *(const uint4*)p;
    return __builtin_bit_cast(bf16x8, v);
}
__device__ __forceinline__ f32x4 MFMA(bf16x8 a, bf16x8 b, f32x4 c){
    return __builtin_amdgcn_mfma_f32_16x16x32_bf16(a, b, c, 0, 0, 0);
}

// ---------------- CSR build ----------------
__global__ void k_hist(const int* __restrict__ edges, int* __restrict__ cnt){
    int e = blockIdx.x*256 + threadIdx.x;
    if (e < NE) atomicAdd(&cnt[edges[NE + e]], 1);
}

__global__ void k_scan1(const int* __restrict__ cnt, int* __restrict__ tmp, int* __restrict__ bsum){
    __shared__ int sh[256];
    int tx = threadIdx.x, i = blockIdx.x*256 + tx;
    int v = (i < NN) ? cnt[i] : 0;
    sh[tx] = v; __syncthreads();
    for (int off = 1; off < 256; off <<= 1){
        int u = (tx >= off) ? sh[tx-off] : 0;
        __syncthreads();
        sh[tx] += u;
        __syncthreads();
    }
    int incl = sh[tx];
    if (i < NN) tmp[i] = incl - v;
    if (tx == 255) bsum[blockIdx.x] = incl;
}

__global__ void k_scan2(const int* __restrict__ bsum, int* __restrict__ boff){
    __shared__ int sh[256];
    int tx = threadIdx.x;
    int v = (tx < SCAN_NBLK) ? bsum[tx] : 0;
    sh[tx] = v; __syncthreads();
    for (int off = 1; off < 256; off <<= 1){
        int u = (tx >= off) ? sh[tx-off] : 0;
        __syncthreads();
        sh[tx] += u;
        __syncthreads();
    }
    boff[tx] = sh[tx] - v;
}

__global__ void k_scan3(const int* __restrict__ tmp, const int* __restrict__ boff,
                        int* __restrict__ row_start, int* __restrict__ cursor){
    int i = blockIdx.x*256 + threadIdx.x;
    if (i < NN){
        int rs = tmp[i] + boff[blockIdx.x];
        row_start[i] = rs;
        cursor[i] = rs;
    }
    if (i == 0) row_start[NN] = NE;
}

__global__ void k_fillcsr(const int* __restrict__ edges, int* __restrict__ cursor, int* __restrict__ csr_src){
    int e = blockIdx.x*256 + threadIdx.x;
    if (e < NE){
        int d = edges[NE + e];
        int pos = atomicAdd(&cursor[d], 1);
        csr_src[pos] = edges[e];
    }
}

// ---------------- weight prep: fp32 -> bf16 (+ transpose for ggc) ----------------
__global__ void k_prep(const float* __restrict__ wih, const float* __restrict__ whh,
                       const float* __restrict__ aiw, const float* __restrict__ ajw,
                       const float* __restrict__ ggc,
                       ushort* __restrict__ wihb, ushort* __restrict__ whhb,
                       ushort* __restrict__ aiwb, ushort* __restrict__ ajwb,
                       ushort* __restrict__ GTb){
    int i = blockIdx.x*256 + threadIdx.x;       // 0..77823
    if (i < 12288)        wihb[i]        = f2bf(wih[i]);
    else if (i < 24576)   whhb[i-12288]  = f2bf(whh[i-12288]);
    else if (i < 40960)   aiwb[i-24576]  = f2bf(aiw[i-24576]);
    else if (i < 57344)   ajwb[i-40960]  = f2bf(ajw[i-40960]);
    else {
        int t = i - 57344;                       // 0..20479
        int mi = t >> 12, rem = t & 4095;
        int n = rem >> 6, k = rem & 63;
        GTb[t] = f2bf(ggc[mi*4096 + k*64 + n]);  // GT[i][n][k] = ggc[i][k][n]
    }
}

// ---------------- x0 build (fp32 + bf16 copies) ----------------
__global__ void k_x0(const float* __restrict__ nodes, float* __restrict__ x0, ushort* __restrict__ x0b){
    int f = blockIdx.x*256 + threadIdx.x;       // float4 index, BN*16 total
    int row = f >> 4, c4 = f & 15;
    int n = row % NN;
    float v[4];
    #pragma unroll
    for (int i = 0; i < 4; ++i){
        int c = c4*4 + i;
        v[i] = (c < NF) ? nodes[(size_t)n*NF + c] : 0.f;
    }
    ((float4*)x0)[f] = make_float4(v[0], v[1], v[2], v[3]);
    uint2 pk;
    pk.x = (uint)f2bf(v[0]) | ((uint)f2bf(v[1]) << 16);
    pk.y = (uint)f2bf(v[2]) | ((uint)f2bf(v[3]) << 16);
    *(uint2*)(x0b + 4*(size_t)f) = pk;
}

__global__ void k_cov(const float* __restrict__ cov, const int* __restrict__ c2l,
                      float* __restrict__ x0, ushort* __restrict__ x0b){
    int i = blockIdx.x*256 + threadIdx.x;
    if (i < NB*NL){
        int b = i / NL, j = i % NL;
        int nd = c2l[j];
        float v = cov[i];
        x0[((size_t)b*NN + nd)*64 + 63] = v;
        x0b[((size_t)b*NN + nd)*64 + 63] = f2bf(v);
    }
}

// ---------------- layer-0 message: m = x0 @ W0  (bf16 MFMA) ----------------
__global__ __launch_bounds__(256) void k_mm0(const ushort* __restrict__ x0b, const ushort* __restrict__ GT0,
                                             ushort* __restrict__ mout){
    __shared__ __align__(16) ushort sA[64*72];
    const int tx = threadIdx.x;
    const int l  = tx & 63, li = l & 15, q = l >> 4;
    const int w  = __builtin_amdgcn_readfirstlane(tx >> 6);
    const size_t row0 = (size_t)blockIdx.x * 64;
    #pragma unroll
    for (int it = 0; it < 2; ++it){
        int idx = it*256 + tx;                   // 0..511
        int r = idx >> 3, g = idx & 7;
        uint4 v = *(const uint4*)(x0b + (row0 + r)*64 + g*8);
        *(uint4*)(&sA[r*72 + g*8]) = v;
    }
    __syncthreads();
    const int n0 = 16*w;
    f32x4 Cm[4];
    #pragma unroll
    for (int m = 0; m < 4; ++m) Cm[m] = (f32x4){0.f,0.f,0.f,0.f};
    #pragma unroll
    for (int ks = 0; ks < 2; ++ks){
        bf16x8 B = ldfrag(GT0 + (size_t)(n0 + li)*64 + ks*32 + q*8);
        #pragma unroll
        for (int m = 0; m < 4; ++m){
            bf16x8 A = ldfrag(&sA[(m*16 + li)*72 + ks*32 + q*8]);
            Cm[m] = MFMA(A, B, Cm[m]);
        }
    }
    const int c = n0 + li;
    #pragma unroll
    for (int m = 0; m < 4; ++m){
        #pragma unroll
        for (int rg = 0; rg < 4; ++rg){
            int rl = m*16 + q*4 + rg;
            size_t rowg = row0 + rl;
            int nidx = (int)(rowg % NN), b = (int)(rowg / NN);
            mout[((size_t)nidx*NB + b)*64 + c] = f2bf(Cm[m][rg]);
        }
    }
}

// ---------------- fused layer: gather-agg + GRU (MFMA) + next-layer message ----------------
__global__ __launch_bounds__(256) void k_layer(const float* __restrict__ xin, const ushort* __restrict__ min_,
                                               const int* __restrict__ row_start, const int* __restrict__ csr_src,
                                               const ushort* __restrict__ wihb, const ushort* __restrict__ whhb,
                                               const float* __restrict__ bih, const float* __restrict__ bhh,
                                               const ushort* __restrict__ GTn, float* __restrict__ xout,
                                               ushort* __restrict__ xb, ushort* __restrict__ mout, int do_m){
    __shared__ __align__(16) ushort sA[64*136];   // [agg | x] bf16, stride 136
    __shared__ float sxf[64*65];                  // x fp32
    const int tx = threadIdx.x;
    const int l  = tx & 63, li = l & 15, q = l >> 4;
    const int w  = __builtin_amdgcn_readfirstlane(tx >> 6);
    const size_t row0 = (size_t)blockIdx.x * 64;

    // stage x (fp32 + bf16 in sA cols 64..127)
    const float4* x4 = (const float4*)(xin + row0*64);
    #pragma unroll
    for (int it = 0; it < 4; ++it){
        int idx = it*256 + tx;                    // 0..1023
        int r = idx >> 4, c4 = idx & 15;
        float4 v = x4[r*16 + c4];
        int fb = r*65 + c4*4;
        sxf[fb+0]=v.x; sxf[fb+1]=v.y; sxf[fb+2]=v.z; sxf[fb+3]=v.w;
        uint2 pk;
        pk.x = (uint)f2bf(v.x) | ((uint)f2bf(v.y) << 16);
        pk.y = (uint)f2bf(v.z) | ((uint)f2bf(v.w) << 16);
        *(uint2*)(&sA[r*136 + 64 + c4*4]) = pk;
    }

    // gather aggregation into sA cols 0..63: wave w owns rows w*16..w*16+15
    {
        const int h = l >> 5, c2 = l & 31;
        const int cc = c2*2;
        for (int i = 0; i < 16; ++i){
            int rw = w*16 + i;
            int rowi = blockIdx.x*64 + rw;
            int n = rowi % NN, b = rowi / NN;
            int e0 = row_start[n], e1 = row_start[n+1];
            float a0 = 0.f, a1 = 0.f;
            int e = e0 + h;
            for (; e + 6 < e1; e += 8){
                int s0 = csr_src[e], s1 = csr_src[e+2], s2 = csr_src[e+4], s3 = csr_src[e+6];
                uint v0 = *(const uint*)(min_ + ((size_t)s0*NB + b)*64 + cc);
                uint v1 = *(const uint*)(min_ + ((size_t)s1*NB + b)*64 + cc);
                uint v2 = *(const uint*)(min_ + ((size_t)s2*NB + b)*64 + cc);
                uint v3 = *(const uint*)(min_ + ((size_t)s3*NB + b)*64 + cc);
                a0 += bf_lo(v0) + bf_lo(v1) + bf_lo(v2) + bf_lo(v3);
                a1 += bf_hi(v0) + bf_hi(v1) + bf_hi(v2) + bf_hi(v3);
            }
            for (; e < e1; e += 2){
                int s0 = csr_src[e];
                uint v0 = *(const uint*)(min_ + ((size_t)s0*NB + b)*64 + cc);
                a0 += bf_lo(v0);
                a1 += bf_hi(v0);
            }
            a0 += __shfl_xor(a0, 32);
            a1 += __shfl_xor(a1, 32);
            if (h == 0){
                uint pk = (uint)f2bf(a0) | ((uint)f2bf(a1) << 16);
                *(uint*)(&sA[rw*136 + cc]) = pk;
            }
        }
    }
    __syncthreads();

    const int n0 = 16*w;
    f32x4 Cr[4], Cz[4], Cxn[4], Chn[4];
    #pragma unroll
    for (int m = 0; m < 4; ++m){
        Cr[m]=(f32x4){0.f,0.f,0.f,0.f}; Cz[m]=(f32x4){0.f,0.f,0.f,0.f};
        Cxn[m]=(f32x4){0.f,0.f,0.f,0.f}; Chn[m]=(f32x4){0.f,0.f,0.f,0.f};
    }
    bf16x8 Bxn[2], Bhn[2];
    #pragma unroll
    for (int ks = 0; ks < 2; ++ks){
        Bxn[ks] = ldfrag(wihb + (size_t)(128 + n0 + li)*64 + ks*32 + q*8);
        Bhn[ks] = ldfrag(whhb + (size_t)(128 + n0 + li)*64 + ks*32 + q*8);
    }
    #pragma unroll
    for (int ks = 0; ks < 4; ++ks){
        const ushort* wb = (ks < 2) ? wihb : whhb;
        int kb = (ks & 1)*32;
        bf16x8 Br = ldfrag(wb + (size_t)(n0 + li)*64 + kb + q*8);
        bf16x8 Bz = ldfrag(wb + (size_t)(64 + n0 + li)*64 + kb + q*8);
        #pragma unroll
        for (int m = 0; m < 4; ++m){
            bf16x8 A = ldfrag(&sA[(m*16 + li)*136 + ks*32 + q*8]);
            Cr[m] = MFMA(A, Br, Cr[m]);
            Cz[m] = MFMA(A, Bz, Cz[m]);
            if (ks < 2) Cxn[m] = MFMA(A, Bxn[ks], Cxn[m]);
            else        Chn[m] = MFMA(A, Bhn[ks-2], Chn[m]);
        }
    }

    const int c = n0 + li;
    const float br_ = bih[c]     + bhh[c];
    const float bz_ = bih[64+c]  + bhh[64+c];
    const float bn_ = bih[128+c];
    const float bh_ = bhh[128+c];
    float xnew[4][4];
    #pragma unroll
    for (int m = 0; m < 4; ++m){
        #pragma unroll
        for (int rg = 0; rg < 4; ++rg){
            int rl = m*16 + q*4 + rg;
            float r = sigm(Cr[m][rg] + br_);
            float z = sigm(Cz[m][rg] + bz_);
            float n = tanhf(Cxn[m][rg] + bn_ + r*(Chn[m][rg] + bh_));
            float xo = sxf[rl*65 + c];
            float v = (1.f - z)*n + z*xo;
            xnew[m][rg] = v;
            if (do_m) xout[(row0 + rl)*64 + c] = v;
        }
    }
    __syncthreads();
    #pragma unroll
    for (int m = 0; m < 4; ++m){
        #pragma unroll
        for (int rg = 0; rg < 4; ++rg){
            int rl = m*16 + q*4 + rg;
            sA[rl*136 + 64 + c] = f2bf(xnew[m][rg]);
        }
    }
    __syncthreads();
    if (do_m){
        f32x4 Cm[4];
        #pragma unroll
        for (int m = 0; m < 4; ++m) Cm[m] = (f32x4){0.f,0.f,0.f,0.f};
        #pragma unroll
        for (int ks = 0; ks < 2; ++ks){
            bf16x8 B = ldfrag(GTn + (size_t)(n0 + li)*64 + ks*32 + q*8);
            #pragma unroll
            for (int m = 0; m < 4; ++m){
                bf16x8 A = ldfrag(&sA[(m*16 + li)*136 + 64 + ks*32 + q*8]);
                Cm[m] = MFMA(A, B, Cm[m]);
            }
        }
        #pragma unroll
        for (int m = 0; m < 4; ++m){
            #pragma unroll
            for (int rg = 0; rg < 4; ++rg){
                int rl = m*16 + q*4 + rg;
                size_t rowg = row0 + rl;
                int nidx = (int)(rowg % NN), b = (int)(rowg / NN);
                mout[((size_t)nidx*NB + b)*64 + c] = f2bf(Cm[m][rg]);
            }
        }
    } else {
        // last layer: dump x' as bf16 for k_att
        #pragma unroll
        for (int it = 0; it < 2; ++it){
            int idx = it*256 + tx;               // 0..511
            int r = idx >> 3, g = idx & 7;
            uint4 v = *(const uint4*)(&sA[r*136 + 64 + g*8]);
            *(uint4*)(xb + (row0 + r)*64 + g*8) = v;
        }
    }
}

// ---------------- attention + pooling (MFMA, bf16 staging) ----------------
__global__ __launch_bounds__(256) void k_att(const ushort* __restrict__ xb, const ushort* __restrict__ x0b,
                                             const ushort* __restrict__ aiwb, const float* __restrict__ aib,
                                             const ushort* __restrict__ ajwb, const float* __restrict__ ajb,
                                             float* __restrict__ pooled){
    __shared__ __align__(16) ushort sC[64*136];   // [x | x0] bf16
    const int tx = threadIdx.x;
    const int l  = tx & 63, li = l & 15, q = l >> 4;
    const int w  = __builtin_amdgcn_readfirstlane(tx >> 6);
    const int b  = blockIdx.x / ATILES;
    const int tb = blockIdx.x % ATILES;
    const int nrow0 = tb*64;
    int nvalid = NN - nrow0; if (nvalid > 64) nvalid = 64;
    const size_t row0 = (size_t)b*NN + nrow0;
    #pragma unroll
    for (int it = 0; it < 4; ++it){
        int idx = it*256 + tx;                    // 0..1023
        int ten = idx >> 9;
        int rem = idx & 511;
        int r = rem >> 3, g = rem & 7;
        uint4 v = make_uint4(0u,0u,0u,0u);
        const ushort* src = ten ? x0b : xb;
        if (r < nvalid) v = *(const uint4*)(src + (row0 + r)*64 + g*8);
        *(uint4*)(&sC[r*136 + ten*64 + g*8]) = v;
    }
    __syncthreads();

    const int nb0 = 32*w;
    f32x4 Ai[2][4], Aj[2][4];
    #pragma unroll
    for (int t = 0; t < 2; ++t)
        #pragma unroll
        for (int m = 0; m < 4; ++m){ Ai[t][m]=(f32x4){0.f,0.f,0.f,0.f}; Aj[t][m]=(f32x4){0.f,0.f,0.f,0.f}; }

    #pragma unroll
    for (int ks = 0; ks < 4; ++ks){
        bf16x8 Bi[2], Bj[2];
        #pragma unroll
        for (int t = 0; t < 2; ++t){
            Bi[t] = ldfrag(aiwb + (size_t)(nb0 + 16*t + li)*128 + ks*32 + q*8);
            Bj[t] = ldfrag(ajwb + (size_t)(nb0 + 16*t + li)*128 + ks*32 + q*8);
        }
        #pragma unroll
        for (int m = 0; m < 4; ++m){
            bf16x8 A = ldfrag(&sC[(m*16 + li)*136 + ks*32 + q*8]);
            #pragma unroll
            for (int t = 0; t < 2; ++t){
                Ai[t][m] = MFMA(A, Bi[t], Ai[t][m]);
                Aj[t][m] = MFMA(A, Bj[t], Aj[t][m]);
            }
        }
    }

    #pragma unroll
    for (int t = 0; t < 2; ++t){
        int c = nb0 + 16*t + li;
        float bia = aib[c], bja = ajb[c];
        float vs = 0.f;
        #pragma unroll
        for (int m = 0; m < 4; ++m){
            #pragma unroll
            for (int rg = 0; rg < 4; ++rg){
                int rl = m*16 + q*4 + rg;
                if (rl < nvalid){
                    float s = sigm(Ai[t][m][rg] + bia);
                    float a = Aj[t][m][rg] + bja;
                    a = a > 0.f ? a : 0.f;
                    vs += s*a;
                }
            }
        }
        vs += __shfl_xor(vs, 16);
        vs += __shfl_xor(vs, 32);
        if (l < 16) atomicAdd(&pooled[b*128 + nb0 + 16*t + l], vs);
    }
}

// ---------------- final MLP + critic ----------------
__global__ __launch_bounds__(256) void k_final(const float* __restrict__ pooled, const float* __restrict__ mw,
                                               const float* __restrict__ mb, const float* __restrict__ cw,
                                               const float* __restrict__ cb, float* __restrict__ out){
    __shared__ float red[256];
    int t = threadIdx.x;
    for (int b = 0; b < NB; ++b){
        float acc = mb[t];
        #pragma unroll 8
        for (int k = 0; k < 128; ++k){
            float p = pooled[b*128 + k];
            p = p > 0.f ? p : 0.f;
            acc = fmaf(p, mw[t*128 + k], acc);
        }
        float st = acc > 0.f ? acc : 0.f;
        red[t] = st * cw[t];
        __syncthreads();
        for (int off = 128; off > 0; off >>= 1){
            if (t < off) red[t] += red[t + off];
            __syncthreads();
        }
        if (t == 0) out[b] = red[0] + cb[0];
        __syncthreads();
    }
}

extern "C" void kernel_launch(void* const* d_in, const int* in_sizes, int n_in,
                              void* d_out, int out_size, void* d_ws, size_t ws_size,
                              hipStream_t stream) {
    const float* cov   = (const float*)d_in[0];
    const float* nodes = (const float*)d_in[1];
    const int*   edges = (const int*)d_in[2];
    const int*   c2l   = (const int*)d_in[3];
    const float* ggc   = (const float*)d_in[4];
    const float* wih   = (const float*)d_in[5];
    const float* whh   = (const float*)d_in[6];
    const float* bih   = (const float*)d_in[7];
    const float* bhh   = (const float*)d_in[8];
    const float* aiw   = (const float*)d_in[9];
    const float* aib   = (const float*)d_in[10];
    const float* ajw   = (const float*)d_in[11];
    const float* ajb   = (const float*)d_in[12];
    const float* mlpw  = (const float*)d_in[13];
    const float* mlpb  = (const float*)d_in[14];
    const float* cw    = (const float*)d_in[15];
    const float* cb    = (const float*)d_in[16];
    float* out = (float*)d_out;

    const size_t XSZ = (size_t)BN * 64;          // 12.8M
    float* ws = (float*)d_ws;
    float* x      = ws;
    float* x0     = ws + XSZ;
    float* pooled = ws + 2*XSZ;                  // 512 floats
    ushort* m0    = (ushort*)(pooled + 512);     // messages ping
    ushort* m1    = m0 + XSZ;                    // messages pong
    ushort* xb    = m1 + XSZ;                    // bf16 final x
    ushort* x0b   = xb + XSZ;                    // bf16 x0
    ushort* wihb  = x0b + XSZ;                   // 12288
    ushort* whhb  = wihb + 12288;                // 12288
    ushort* aiwb  = whhb + 12288;                // 16384
    ushort* ajwb  = aiwb + 16384;                // 16384
    ushort* GTb   = ajwb + 16384;                // 20480
    int* cnt       = (int*)(GTb + 20480);
    int* tmp       = cnt + NN;
    int* bsum      = tmp + NN;
    int* boff      = bsum + 256;
    int* row_start = boff + 256;
    int* cursor    = row_start + (NN + 1);
    int* csr_src   = cursor + NN;

    hipMemsetAsync(cnt, 0, (size_t)NN*sizeof(int), stream);
    hipMemsetAsync(pooled, 0, 512*sizeof(float), stream);

    k_prep<<<304, 256, 0, stream>>>(wih, whh, aiw, ajw, ggc, wihb, whhb, aiwb, ajwb, GTb);

    k_hist<<<(NE + 255)/256, 256, 0, stream>>>(edges, cnt);
    k_scan1<<<SCAN_NBLK, 256, 0, stream>>>(cnt, tmp, bsum);
    k_scan2<<<1, 256, 0, stream>>>(bsum, boff);
    k_scan3<<<SCAN_NBLK, 256, 0, stream>>>(tmp, boff, row_start, cursor);
    k_fillcsr<<<(NE + 255)/256, 256, 0, stream>>>(edges, cursor, csr_src);

    k_x0<<<(BN*16)/256, 256, 0, stream>>>(nodes, x0, x0b);
    k_cov<<<(NB*NL + 255)/256, 256, 0, stream>>>(cov, c2l, x0, x0b);

    k_mm0<<<NTILES, 256, 0, stream>>>(x0b, GTb, m0);

    for (int i = 0; i < NLAY; ++i){
        const float* xin = (i == 0) ? x0 : x;
        int do_m = (i < NLAY - 1);
        const ushort* min_ = (i & 1) ? m1 : m0;
        ushort* mout       = (i & 1) ? m0 : m1;
        const ushort* GTn = GTb + (size_t)(do_m ? (i + 1) : 0)*4096;
        k_layer<<<NTILES, 256, 0, stream>>>(xin, min_, row_start, csr_src,
                                            wihb, whhb, bih, bhh, GTn,
                                            x, xb, mout, do_m);
    }

    k_att<<<NB*ATILES, 256, 0, stream>>>(xb, x0b, aiwb, aib, ajwb, ajb, pooled);
    k_final<<<1, 256, 0, stream>>>(pooled, mlpw, mlpb, cw, cb, out);
    (void)in_sizes; (void)n_in; (void)out_size; (void)ws_size;
}

// Round 4
// 769.687 us; speedup vs baseline: 2.3829x; 2.3829x over previous
//
#include <hip/hip_runtime.h>
#include <math.h>

#define NN 50000
#define NF 63
#define NE 800000
#define NL 10000
#define NB 4
#define NLAY 5
#define BN (NB*NN)                 // 200000 rows
#define NTILES (BN/64)             // 3125
#define SCAN_NBLK ((NN+255)/256)   // 196
#define ATILES ((NN+63)/64)        // 782

using f32x4  = __attribute__((ext_vector_type(4))) float;
using bf16x8 = __attribute__((ext_vector_type(8))) __bf16;

__device__ __forceinline__ float frcp(float x){ return __builtin_amdgcn_rcpf(x); }
__device__ __forceinline__ float sigm(float v){ return frcp(1.f + __expf(-v)); }
__device__ __forceinline__ float tanh_f(float v){ return fmaf(-2.f, frcp(__expf(2.f*v) + 1.f), 1.f); }

__device__ __forceinline__ ushort f2bf(float f){
    uint u = __builtin_bit_cast(uint, f);
    u += 0x7fffu + ((u >> 16) & 1u);
    return (ushort)(u >> 16);
}
__device__ __forceinline__ float bf_lo(uint v){ return __builtin_bit_cast(float, v << 16); }
__device__ __forceinline__ float bf_hi(uint v){ return __builtin_bit_cast(float, v & 0xffff0000u); }

__device__ __forceinline__ bf16x8 ldfrag(const ushort* p){
    uint4 v = *(const uint4*)p;
    return __builtin_bit_cast(bf16x8, v);
}
__device__ __forceinline__ f32x4 MFMA(bf16x8 a, bf16x8 b, f32x4 c){
    return __builtin_amdgcn_mfma_f32_16x16x32_bf16(a, b, c, 0, 0, 0);
}

// ---------------- CSR build ----------------
__global__ void k_hist(const int* __restrict__ edges, int* __restrict__ cnt){
    int e = blockIdx.x*256 + threadIdx.x;
    if (e < NE) atomicAdd(&cnt[edges[NE + e]], 1);
}

__global__ void k_scan1(const int* __restrict__ cnt, int* __restrict__ tmp, int* __restrict__ bsum){
    __shared__ int sh[256];
    int tx = threadIdx.x, i = blockIdx.x*256 + tx;
    int v = (i < NN) ? cnt[i] : 0;
    sh[tx] = v; __syncthreads();
    for (int off = 1; off < 256; off <<= 1){
        int u = (tx >= off) ? sh[tx-off] : 0;
        __syncthreads();
        sh[tx] += u;
        __syncthreads();
    }
    int incl = sh[tx];
    if (i < NN) tmp[i] = incl - v;
    if (tx == 255) bsum[blockIdx.x] = incl;
}

__global__ void k_scan2(const int* __restrict__ bsum, int* __restrict__ boff){
    __shared__ int sh[256];
    int tx = threadIdx.x;
    int v = (tx < SCAN_NBLK) ? bsum[tx] : 0;
    sh[tx] = v; __syncthreads();
    for (int off = 1; off < 256; off <<= 1){
        int u = (tx >= off) ? sh[tx-off] : 0;
        __syncthreads();
        sh[tx] += u;
        __syncthreads();
    }
    boff[tx] = sh[tx] - v;
}

__global__ void k_scan3(const int* __restrict__ tmp, const int* __restrict__ boff,
                        int* __restrict__ row_start, int* __restrict__ cursor){
    int i = blockIdx.x*256 + threadIdx.x;
    if (i < NN){
        int rs = tmp[i] + boff[blockIdx.x];
        row_start[i] = rs;
        cursor[i] = rs;
    }
    if (i == 0) row_start[NN] = NE;
}

__global__ void k_fillcsr(const int* __restrict__ edges, int* __restrict__ cursor, int* __restrict__ csr_src){
    int e = blockIdx.x*256 + threadIdx.x;
    if (e < NE){
        int d = edges[NE + e];
        int pos = atomicAdd(&cursor[d], 1);
        csr_src[pos] = edges[e];
    }
}

// ---------------- weight prep ----------------
// wfb[i][n][k] = sum_c ggc[i][k][c] * wih[n][c]   (fused: agg_x @ wfb^T == (agg_x@W) @ wih^T)
__global__ void k_prep(const float* __restrict__ wih, const float* __restrict__ whh,
                       const float* __restrict__ aiw, const float* __restrict__ ajw,
                       const float* __restrict__ ggc,
                       ushort* __restrict__ whhb, ushort* __restrict__ aiwb,
                       ushort* __restrict__ ajwb, ushort* __restrict__ wfb){
    int i = blockIdx.x*256 + threadIdx.x;       // 0..106495
    if (i < 12288)        whhb[i]        = f2bf(whh[i]);
    else if (i < 28672)   aiwb[i-12288]  = f2bf(aiw[i-12288]);
    else if (i < 45056)   ajwb[i-28672]  = f2bf(ajw[i-28672]);
    else {
        int t = i - 45056;                       // 0..61439
        int lay = t / 12288;
        int rem = t % 12288;
        int n = rem >> 6, k = rem & 63;
        const float* W  = ggc + lay*4096 + k*64;
        const float* wr = wih + n*64;
        float s = 0.f;
        #pragma unroll 8
        for (int c = 0; c < 64; ++c) s = fmaf(W[c], wr[c], s);
        wfb[t] = f2bf(s);
    }
}

// ---------------- x0 build (fp32 flat + bf16 flat + bf16 interleaved) ----------------
__global__ void k_x0(const float* __restrict__ nodes, float* __restrict__ x0,
                     ushort* __restrict__ x0b, ushort* __restrict__ x0I){
    int f = blockIdx.x*256 + threadIdx.x;       // float4 index, BN*16 total
    int row = f >> 4, c4 = f & 15;
    int n = row % NN, b = row / NN;
    float v[4];
    #pragma unroll
    for (int i = 0; i < 4; ++i){
        int c = c4*4 + i;
        v[i] = (c < NF) ? nodes[(size_t)n*NF + c] : 0.f;
    }
    ((float4*)x0)[f] = make_float4(v[0], v[1], v[2], v[3]);
    uint2 pk;
    pk.x = (uint)f2bf(v[0]) | ((uint)f2bf(v[1]) << 16);
    pk.y = (uint)f2bf(v[2]) | ((uint)f2bf(v[3]) << 16);
    *(uint2*)(x0b + 4*(size_t)f) = pk;
    *(uint2*)(x0I + ((size_t)n*4 + b)*64 + c4*4) = pk;
}

__global__ void k_cov(const float* __restrict__ cov, const int* __restrict__ c2l,
                      float* __restrict__ x0, ushort* __restrict__ x0b, ushort* __restrict__ x0I){
    int i = blockIdx.x*256 + threadIdx.x;
    if (i < NB*NL){
        int b = i / NL, j = i % NL;
        int nd = c2l[j];
        float v = cov[i];
        ushort vb = f2bf(v);
        x0[((size_t)b*NN + nd)*64 + 63] = v;
        x0b[((size_t)b*NN + nd)*64 + 63] = vb;
        x0I[((size_t)nd*4 + b)*64 + 63] = vb;
    }
}

// ---------------- agg_x = gather-sum of node states (bf16, interleaved records) ----------------
// one wave per dst; half-wave per edge (full 512B record); 4 records in flight per half
__global__ __launch_bounds__(256) void k_agg(const ushort* __restrict__ xI,
                                             const int* __restrict__ row_start,
                                             const int* __restrict__ csr_src,
                                             ushort* __restrict__ aggx){
    int tx = threadIdx.x, l = tx & 63, w = tx >> 6;
    int d = __builtin_amdgcn_readfirstlane(blockIdx.x*4 + w);
    int h = l >> 5;                     // half-wave: even/odd edges
    int t = l & 31;                     // b = t>>3, c8 = t&7 ; record offset = t*8 ushorts
    const uint off = (uint)(t*8);
    int e0 = row_start[d], e1 = row_start[d+1];
    float a0=0.f,a1=0.f,a2=0.f,a3=0.f,a4=0.f,a5=0.f,a6=0.f,a7=0.f;
    int e = e0 + h;
    for (; e + 6 < e1; e += 8){
        int s0 = csr_src[e], s1 = csr_src[e+2], s2 = csr_src[e+4], s3 = csr_src[e+6];
        uint4 v0 = *(const uint4*)(xI + (size_t)s0*256 + off);
        uint4 v1 = *(const uint4*)(xI + (size_t)s1*256 + off);
        uint4 v2 = *(const uint4*)(xI + (size_t)s2*256 + off);
        uint4 v3 = *(const uint4*)(xI + (size_t)s3*256 + off);
        a0 += bf_lo(v0.x)+bf_lo(v1.x)+bf_lo(v2.x)+bf_lo(v3.x);
        a1 += bf_hi(v0.x)+bf_hi(v1.x)+bf_hi(v2.x)+bf_hi(v3.x);
        a2 += bf_lo(v0.y)+bf_lo(v1.y)+bf_lo(v2.y)+bf_lo(v3.y);
        a3 += bf_hi(v0.y)+bf_hi(v1.y)+bf_hi(v2.y)+bf_hi(v3.y);
        a4 += bf_lo(v0.z)+bf_lo(v1.z)+bf_lo(v2.z)+bf_lo(v3.z);
        a5 += bf_hi(v0.z)+bf_hi(v1.z)+bf_hi(v2.z)+bf_hi(v3.z);
        a6 += bf_lo(v0.w)+bf_lo(v1.w)+bf_lo(v2.w)+bf_lo(v3.w);
        a7 += bf_hi(v0.w)+bf_hi(v1.w)+bf_hi(v2.w)+bf_hi(v3.w);
    }
    for (; e < e1; e += 2){
        int s0 = csr_src[e];
        uint4 v0 = *(const uint4*)(xI + (size_t)s0*256 + off);
        a0 += bf_lo(v0.x); a1 += bf_hi(v0.x);
        a2 += bf_lo(v0.y); a3 += bf_hi(v0.y);
        a4 += bf_lo(v0.z); a5 += bf_hi(v0.z);
        a6 += bf_lo(v0.w); a7 += bf_hi(v0.w);
    }
    a0 += __shfl_xor(a0, 32); a1 += __shfl_xor(a1, 32);
    a2 += __shfl_xor(a2, 32); a3 += __shfl_xor(a3, 32);
    a4 += __shfl_xor(a4, 32); a5 += __shfl_xor(a5, 32);
    a6 += __shfl_xor(a6, 32); a7 += __shfl_xor(a7, 32);
    if (h == 0){
        uint4 o;
        o.x = (uint)f2bf(a0) | ((uint)f2bf(a1) << 16);
        o.y = (uint)f2bf(a2) | ((uint)f2bf(a3) << 16);
        o.z = (uint)f2bf(a4) | ((uint)f2bf(a5) << 16);
        o.w = (uint)f2bf(a6) | ((uint)f2bf(a7) << 16);
        int b = t >> 3, c8 = t & 7;
        *(uint4*)(aggx + ((size_t)b*NN + d)*64 + c8*8) = o;
    }
}

// ---------------- GRU layer (MFMA, fused weights) ----------------
__global__ __launch_bounds__(256) void k_gru(const float* __restrict__ xin, const ushort* __restrict__ aggx,
                                             const ushort* __restrict__ wfb, const ushort* __restrict__ whhb,
                                             const float* __restrict__ bih, const float* __restrict__ bhh,
                                             float* __restrict__ xout, ushort* __restrict__ xIout,
                                             ushort* __restrict__ xb, int last){
    __shared__ __align__(16) ushort sA[64*136];   // cols 0..63: agg_x ; cols 64..127: x (bf16)
    __shared__ float sxf[64*65];                  // x fp32
    const int tx = threadIdx.x;
    const int l  = tx & 63, li = l & 15, q = l >> 4;
    const int w  = __builtin_amdgcn_readfirstlane(tx >> 6);
    const size_t row0 = (size_t)blockIdx.x * 64;

    #pragma unroll
    for (int it = 0; it < 2; ++it){
        int idx = it*256 + tx;                    // 0..511
        int r = idx >> 3, g = idx & 7;
        uint4 v = *(const uint4*)(aggx + (row0 + r)*64 + g*8);
        *(uint4*)(&sA[r*136 + g*8]) = v;
    }
    const float4* x4 = (const float4*)(xin + row0*64);
    #pragma unroll
    for (int it = 0; it < 4; ++it){
        int idx = it*256 + tx;                    // 0..1023
        int r = idx >> 4, c4 = idx & 15;
        float4 v = x4[r*16 + c4];
        int fb = r*65 + c4*4;
        sxf[fb+0]=v.x; sxf[fb+1]=v.y; sxf[fb+2]=v.z; sxf[fb+3]=v.w;
        uint2 pk;
        pk.x = (uint)f2bf(v.x) | ((uint)f2bf(v.y) << 16);
        pk.y = (uint)f2bf(v.z) | ((uint)f2bf(v.w) << 16);
        *(uint2*)(&sA[r*136 + 64 + c4*4]) = pk;
    }
    __syncthreads();

    const int n0 = 16*w;
    f32x4 Cr[4], Cz[4], Cxn[4], Chn[4];
    #pragma unroll
    for (int m = 0; m < 4; ++m){
        Cr[m]=(f32x4){0.f,0.f,0.f,0.f}; Cz[m]=(f32x4){0.f,0.f,0.f,0.f};
        Cxn[m]=(f32x4){0.f,0.f,0.f,0.f}; Chn[m]=(f32x4){0.f,0.f,0.f,0.f};
    }
    bf16x8 Bxn[2], Bhn[2];
    #pragma unroll
    for (int ks = 0; ks < 2; ++ks){
        Bxn[ks] = ldfrag(wfb  + (size_t)(128 + n0 + li)*64 + ks*32 + q*8);
        Bhn[ks] = ldfrag(whhb + (size_t)(128 + n0 + li)*64 + ks*32 + q*8);
    }
    #pragma unroll
    for (int ks = 0; ks < 4; ++ks){
        const ushort* wb = (ks < 2) ? wfb : whhb;
        int kb = (ks & 1)*32;
        bf16x8 Br = ldfrag(wb + (size_t)(n0 + li)*64 + kb + q*8);
        bf16x8 Bz = ldfrag(wb + (size_t)(64 + n0 + li)*64 + kb + q*8);
        #pragma unroll
        for (int m = 0; m < 4; ++m){
            bf16x8 A = ldfrag(&sA[(m*16 + li)*136 + ks*32 + q*8]);
            Cr[m] = MFMA(A, Br, Cr[m]);
            Cz[m] = MFMA(A, Bz, Cz[m]);
            if (ks < 2) Cxn[m] = MFMA(A, Bxn[ks], Cxn[m]);
            else        Chn[m] = MFMA(A, Bhn[ks-2], Chn[m]);
        }
    }

    const int c = n0 + li;
    const float br_ = bih[c]     + bhh[c];
    const float bz_ = bih[64+c]  + bhh[64+c];
    const float bn_ = bih[128+c];
    const float bh_ = bhh[128+c];
    float xnew[4][4];
    #pragma unroll
    for (int m = 0; m < 4; ++m){
        #pragma unroll
        for (int rg = 0; rg < 4; ++rg){
            int rl = m*16 + q*4 + rg;
            float r = sigm(Cr[m][rg] + br_);
            float z = sigm(Cz[m][rg] + bz_);
            float n = tanh_f(Cxn[m][rg] + bn_ + r*(Chn[m][rg] + bh_));
            float xo = sxf[rl*65 + c];
            float v = (1.f - z)*n + z*xo;
            xnew[m][rg] = v;
            if (!last) xout[(row0 + rl)*64 + c] = v;
        }
    }
    __syncthreads();
    #pragma unroll
    for (int m = 0; m < 4; ++m){
        #pragma unroll
        for (int rg = 0; rg < 4; ++rg){
            int rl = m*16 + q*4 + rg;
            sA[rl*136 + c] = f2bf(xnew[m][rg]);
        }
    }
    __syncthreads();
    if (!last){
        // interleaved bf16 dump for next layer's gather
        #pragma unroll
        for (int it = 0; it < 2; ++it){
            int idx = it*256 + tx;               // 0..511
            int r = idx >> 3, g = idx & 7;
            int rowg = (int)row0 + r;
            int n = rowg % NN, b = rowg / NN;
            uint4 v = *(const uint4*)(&sA[r*136 + g*8]);
            *(uint4*)(xIout + ((size_t)n*4 + b)*64 + g*8) = v;
        }
    } else {
        // flat bf16 dump for k_att
        #pragma unroll
        for (int it = 0; it < 2; ++it){
            int idx = it*256 + tx;               // 0..511
            int r = idx >> 3, g = idx & 7;
            uint4 v = *(const uint4*)(&sA[r*136 + g*8]);
            *(uint4*)(xb + (row0 + r)*64 + g*8) = v;
        }
    }
}

// ---------------- attention + pooling (MFMA, bf16 staging) ----------------
__global__ __launch_bounds__(256) void k_att(const ushort* __restrict__ xb, const ushort* __restrict__ x0b,
                                             const ushort* __restrict__ aiwb, const float* __restrict__ aib,
                                             const ushort* __restrict__ ajwb, const float* __restrict__ ajb,
                                             float* __restrict__ pooled){
    __shared__ __align__(16) ushort sC[64*136];   // [x | x0] bf16
    const int tx = threadIdx.x;
    const int l  = tx & 63, li = l & 15, q = l >> 4;
    const int w  = __builtin_amdgcn_readfirstlane(tx >> 6);
    const int b  = blockIdx.x / ATILES;
    const int tb = blockIdx.x % ATILES;
    const int nrow0 = tb*64;
    int nvalid = NN - nrow0; if (nvalid > 64) nvalid = 64;
    const size_t row0 = (size_t)b*NN + nrow0;
    #pragma unroll
    for (int it = 0; it < 4; ++it){
        int idx = it*256 + tx;                    // 0..1023
        int ten = idx >> 9;
        int rem = idx & 511;
        int r = rem >> 3, g = rem & 7;
        uint4 v = make_uint4(0u,0u,0u,0u);
        const ushort* src = ten ? x0b : xb;
        if (r < nvalid) v = *(const uint4*)(src + (row0 + r)*64 + g*8);
        *(uint4*)(&sC[r*136 + ten*64 + g*8]) = v;
    }
    __syncthreads();

    const int nb0 = 32*w;
    f32x4 Ai[2][4], Aj[2][4];
    #pragma unroll
    for (int t = 0; t < 2; ++t)
        #pragma unroll
        for (int m = 0; m < 4; ++m){ Ai[t][m]=(f32x4){0.f,0.f,0.f,0.f}; Aj[t][m]=(f32x4){0.f,0.f,0.f,0.f}; }

    #pragma unroll
    for (int ks = 0; ks < 4; ++ks){
        bf16x8 Bi[2], Bj[2];
        #pragma unroll
        for (int t = 0; t < 2; ++t){
            Bi[t] = ldfrag(aiwb + (size_t)(nb0 + 16*t + li)*128 + ks*32 + q*8);
            Bj[t] = ldfrag(ajwb + (size_t)(nb0 + 16*t + li)*128 + ks*32 + q*8);
        }
        #pragma unroll
        for (int m = 0; m < 4; ++m){
            bf16x8 A = ldfrag(&sC[(m*16 + li)*136 + ks*32 + q*8]);
            #pragma unroll
            for (int t = 0; t < 2; ++t){
                Ai[t][m] = MFMA(A, Bi[t], Ai[t][m]);
                Aj[t][m] = MFMA(A, Bj[t], Aj[t][m]);
            }
        }
    }

    #pragma unroll
    for (int t = 0; t < 2; ++t){
        int c = nb0 + 16*t + li;
        float bia = aib[c], bja = ajb[c];
        float vs = 0.f;
        #pragma unroll
        for (int m = 0; m < 4; ++m){
            #pragma unroll
            for (int rg = 0; rg < 4; ++rg){
                int rl = m*16 + q*4 + rg;
                if (rl < nvalid){
                    float s = sigm(Ai[t][m][rg] + bia);
                    float a = Aj[t][m][rg] + bja;
                    a = a > 0.f ? a : 0.f;
                    vs += s*a;
                }
            }
        }
        vs += __shfl_xor(vs, 16);
        vs += __shfl_xor(vs, 32);
        if (l < 16) atomicAdd(&pooled[b*128 + nb0 + 16*t + l], vs);
    }
}

// ---------------- final MLP + critic ----------------
__global__ __launch_bounds__(256) void k_final(const float* __restrict__ pooled, const float* __restrict__ mw,
                                               const float* __restrict__ mb, const float* __restrict__ cw,
                                               const float* __restrict__ cb, float* __restrict__ out){
    __shared__ float red[256];
    int t = threadIdx.x;
    for (int b = 0; b < NB; ++b){
        float acc = mb[t];
        #pragma unroll 8
        for (int k = 0; k < 128; ++k){
            float p = pooled[b*128 + k];
            p = p > 0.f ? p : 0.f;
            acc = fmaf(p, mw[t*128 + k], acc);
        }
        float st = acc > 0.f ? acc : 0.f;
        red[t] = st * cw[t];
        __syncthreads();
        for (int off = 128; off > 0; off >>= 1){
            if (t < off) red[t] += red[t + off];
            __syncthreads();
        }
        if (t == 0) out[b] = red[0] + cb[0];
        __syncthreads();
    }
}

extern "C" void kernel_launch(void* const* d_in, const int* in_sizes, int n_in,
                              void* d_out, int out_size, void* d_ws, size_t ws_size,
                              hipStream_t stream) {
    const float* cov   = (const float*)d_in[0];
    const float* nodes = (const float*)d_in[1];
    const int*   edges = (const int*)d_in[2];
    const int*   c2l   = (const int*)d_in[3];
    const float* ggc   = (const float*)d_in[4];
    const float* wih   = (const float*)d_in[5];
    const float* whh   = (const float*)d_in[6];
    const float* bih   = (const float*)d_in[7];
    const float* bhh   = (const float*)d_in[8];
    const float* aiw   = (const float*)d_in[9];
    const float* aib   = (const float*)d_in[10];
    const float* ajw   = (const float*)d_in[11];
    const float* ajb   = (const float*)d_in[12];
    const float* mlpw  = (const float*)d_in[13];
    const float* mlpb  = (const float*)d_in[14];
    const float* cw    = (const float*)d_in[15];
    const float* cb    = (const float*)d_in[16];
    float* out = (float*)d_out;

    const size_t XSZ = (size_t)BN * 64;          // 12.8M
    float* ws = (float*)d_ws;
    float* x      = ws;                          // fp32 state
    float* x0     = ws + XSZ;
    float* pooled = ws + 2*XSZ;                  // 512 floats
    ushort* xI    = (ushort*)(pooled + 512);     // bf16 interleaved state [n][b][64]
    ushort* x0I   = xI + XSZ;
    ushort* aggx  = x0I + XSZ;                   // bf16 agg of x, [b*NN+n][64]
    ushort* xb    = aggx + XSZ;                  // bf16 flat final x
    ushort* x0b   = xb + XSZ;                    // bf16 flat x0
    ushort* whhb  = x0b + XSZ;                   // 12288
    ushort* aiwb  = whhb + 12288;                // 16384
    ushort* ajwb  = aiwb + 16384;                // 16384
    ushort* wfb   = ajwb + 16384;                // 5*12288 fused ih weights
    int* cnt       = (int*)(wfb + 61440);
    int* tmp       = cnt + NN;
    int* bsum      = tmp + NN;
    int* boff      = bsum + 256;
    int* row_start = boff + 256;
    int* cursor    = row_start + (NN + 1);
    int* csr_src   = cursor + NN;

    hipMemsetAsync(cnt, 0, (size_t)NN*sizeof(int), stream);
    hipMemsetAsync(pooled, 0, 512*sizeof(float), stream);

    k_prep<<<416, 256, 0, stream>>>(wih, whh, aiw, ajw, ggc, whhb, aiwb, ajwb, wfb);

    k_hist<<<(NE + 255)/256, 256, 0, stream>>>(edges, cnt);
    k_scan1<<<SCAN_NBLK, 256, 0, stream>>>(cnt, tmp, bsum);
    k_scan2<<<1, 256, 0, stream>>>(bsum, boff);
    k_scan3<<<SCAN_NBLK, 256, 0, stream>>>(tmp, boff, row_start, cursor);
    k_fillcsr<<<(NE + 255)/256, 256, 0, stream>>>(edges, cursor, csr_src);

    k_x0<<<(BN*16)/256, 256, 0, stream>>>(nodes, x0, x0b, x0I);
    k_cov<<<(NB*NL + 255)/256, 256, 0, stream>>>(cov, c2l, x0, x0b, x0I);

    for (int i = 0; i < NLAY; ++i){
        const ushort* gsrc = (i == 0) ? x0I : xI;
        const float*  xin  = (i == 0) ? x0  : x;
        int last = (i == NLAY - 1);
        k_agg<<<NN/4, 256, 0, stream>>>(gsrc, row_start, csr_src, aggx);
        k_gru<<<NTILES, 256, 0, stream>>>(xin, aggx, wfb + (size_t)i*12288, whhb,
                                          bih, bhh, x, xI, xb, last);
    }

    k_att<<<NB*ATILES, 256, 0, stream>>>(xb, x0b, aiwb, aib, ajwb, ajb, pooled);
    k_final<<<1, 256, 0, stream>>>(pooled, mlpw, mlpb, cw, cb, out);
    (void)in_sizes; (void)n_in; (void)out_size; (void)ws_size;
}

// Round 5
// 724.598 us; speedup vs baseline: 2.5311x; 1.0622x over previous
//
#include <hip/hip_runtime.h>
#include <math.h>

#define NN 50000
#define NF 63
#define NE 800000
#define NL 10000
#define NB 4
#define NLAY 5
#define BN (NB*NN)                 // 200000 rows
#define NTILES (BN/64)             // 3125
#define SCAN_NBLK ((NN+255)/256)   // 196

using f32x4  = __attribute__((ext_vector_type(4))) float;
using bf16x8 = __attribute__((ext_vector_type(8))) __bf16;

__device__ __forceinline__ float frcp(float x){ return __builtin_amdgcn_rcpf(x); }
__device__ __forceinline__ float sigm(float v){ return frcp(1.f + __expf(-v)); }
__device__ __forceinline__ float tanh_f(float v){ return fmaf(-2.f, frcp(__expf(2.f*v) + 1.f), 1.f); }

__device__ __forceinline__ ushort f2bf(float f){
    uint u = __builtin_bit_cast(uint, f);
    u += 0x7fffu + ((u >> 16) & 1u);
    return (ushort)(u >> 16);
}
__device__ __forceinline__ float bf_lo(uint v){ return __builtin_bit_cast(float, v << 16); }
__device__ __forceinline__ float bf_hi(uint v){ return __builtin_bit_cast(float, v & 0xffff0000u); }

__device__ __forceinline__ bf16x8 ldfrag(const ushort* p){
    uint4 v = *(const uint4*)p;
    return __builtin_bit_cast(bf16x8, v);
}
__device__ __forceinline__ f32x4 MFMA(bf16x8 a, bf16x8 b, f32x4 c){
    return __builtin_amdgcn_mfma_f32_16x16x32_bf16(a, b, c, 0, 0, 0);
}

// ---------------- CSR build ----------------
__global__ void k_hist(const int* __restrict__ edges, int* __restrict__ cnt){
    int e = blockIdx.x*256 + threadIdx.x;
    if (e < NE) atomicAdd(&cnt[edges[NE + e]], 1);
}

__global__ void k_scan1(const int* __restrict__ cnt, int* __restrict__ tmp, int* __restrict__ bsum){
    __shared__ int sh[256];
    int tx = threadIdx.x, i = blockIdx.x*256 + tx;
    int v = (i < NN) ? cnt[i] : 0;
    sh[tx] = v; __syncthreads();
    for (int off = 1; off < 256; off <<= 1){
        int u = (tx >= off) ? sh[tx-off] : 0;
        __syncthreads();
        sh[tx] += u;
        __syncthreads();
    }
    int incl = sh[tx];
    if (i < NN) tmp[i] = incl - v;
    if (tx == 255) bsum[blockIdx.x] = incl;
}

__global__ void k_scan2(const int* __restrict__ bsum, int* __restrict__ boff){
    __shared__ int sh[256];
    int tx = threadIdx.x;
    int v = (tx < SCAN_NBLK) ? bsum[tx] : 0;
    sh[tx] = v; __syncthreads();
    for (int off = 1; off < 256; off <<= 1){
        int u = (tx >= off) ? sh[tx-off] : 0;
        __syncthreads();
        sh[tx] += u;
        __syncthreads();
    }
    boff[tx] = sh[tx] - v;
}

__global__ void k_scan3(const int* __restrict__ tmp, const int* __restrict__ boff,
                        int* __restrict__ row_start, int* __restrict__ cursor){
    int i = blockIdx.x*256 + threadIdx.x;
    if (i < NN){
        int rs = tmp[i] + boff[blockIdx.x];
        row_start[i] = rs;
        cursor[i] = rs;
    }
    if (i == 0) row_start[NN] = NE;
}

__global__ void k_fillcsr(const int* __restrict__ edges, int* __restrict__ cursor, int* __restrict__ csr_src){
    int e = blockIdx.x*256 + threadIdx.x;
    if (e < NE){
        int d = edges[NE + e];
        int pos = atomicAdd(&cursor[d], 1);
        csr_src[pos] = edges[e];
    }
}

// ---------------- weight prep ----------------
// wfb[i][n][k] = sum_c ggc[i][k][c] * wih[n][c]   (agg_x @ wfb^T == (agg_x@W_i) @ wih^T)
__global__ void k_prep(const float* __restrict__ wih, const float* __restrict__ whh,
                       const float* __restrict__ aiw, const float* __restrict__ ajw,
                       const float* __restrict__ ggc,
                       ushort* __restrict__ whhb, ushort* __restrict__ aiwb,
                       ushort* __restrict__ ajwb, ushort* __restrict__ wfb){
    int i = blockIdx.x*256 + threadIdx.x;       // 0..106495
    if (i < 12288)        whhb[i]        = f2bf(whh[i]);
    else if (i < 28672)   aiwb[i-12288]  = f2bf(aiw[i-12288]);
    else if (i < 45056)   ajwb[i-28672]  = f2bf(ajw[i-28672]);
    else {
        int t = i - 45056;                       // 0..61439
        int lay = t / 12288;
        int rem = t % 12288;
        int n = rem >> 6, k = rem & 63;
        const float* W  = ggc + lay*4096 + k*64;
        const float* wr = wih + n*64;
        float s = 0.f;
        #pragma unroll 8
        for (int c = 0; c < 64; ++c) s = fmaf(W[c], wr[c], s);
        wfb[t] = f2bf(s);
    }
}

// ---------------- x0 build (bf16 interleaved only) ----------------
__global__ void k_x0(const float* __restrict__ nodes, ushort* __restrict__ x0I){
    int f = blockIdx.x*256 + threadIdx.x;       // 8B group index, BN*16 total
    int row = f >> 4, c4 = f & 15;
    int n = row % NN, b = row / NN;
    float v[4];
    #pragma unroll
    for (int i = 0; i < 4; ++i){
        int c = c4*4 + i;
        v[i] = (c < NF) ? nodes[(size_t)n*NF + c] : 0.f;
    }
    uint2 pk;
    pk.x = (uint)f2bf(v[0]) | ((uint)f2bf(v[1]) << 16);
    pk.y = (uint)f2bf(v[2]) | ((uint)f2bf(v[3]) << 16);
    *(uint2*)(x0I + ((size_t)n*4 + b)*64 + c4*4) = pk;
}

__global__ void k_cov(const float* __restrict__ cov, const int* __restrict__ c2l,
                      ushort* __restrict__ x0I){
    int i = blockIdx.x*256 + threadIdx.x;
    if (i < NB*NL){
        int b = i / NL, j = i % NL;
        int nd = c2l[j];
        x0I[((size_t)nd*4 + b)*64 + 63] = f2bf(cov[i]);
    }
}

// ---------------- agg_x: gather-sum of node states (full wave per edge record) ----------------
__global__ __launch_bounds__(256) void k_agg(const ushort* __restrict__ xI,
                                             const int* __restrict__ row_start,
                                             const int* __restrict__ csr_src,
                                             ushort* __restrict__ aggx){
    int tx = threadIdx.x, l = tx & 63, w = tx >> 6;
    int d = __builtin_amdgcn_readfirstlane(blockIdx.x*4 + w);
    const uint off = (uint)(l*4);       // 8 B per lane; lane l covers b=l>>4, cols (l&15)*4..+3
    int e0 = row_start[d], e1 = row_start[d+1];
    float a0=0.f,a1=0.f,a2=0.f,a3=0.f;
    int e = e0;
    for (; e + 7 < e1; e += 8){
        int s[8];
        #pragma unroll
        for (int j = 0; j < 8; ++j) s[j] = csr_src[e+j];
        uint2 v[8];
        #pragma unroll
        for (int j = 0; j < 8; ++j) v[j] = *(const uint2*)(xI + (size_t)s[j]*256 + off);
        #pragma unroll
        for (int j = 0; j < 8; ++j){
            a0 += bf_lo(v[j].x); a1 += bf_hi(v[j].x);
            a2 += bf_lo(v[j].y); a3 += bf_hi(v[j].y);
        }
    }
    for (; e + 3 < e1; e += 4){
        int s[4];
        #pragma unroll
        for (int j = 0; j < 4; ++j) s[j] = csr_src[e+j];
        uint2 v[4];
        #pragma unroll
        for (int j = 0; j < 4; ++j) v[j] = *(const uint2*)(xI + (size_t)s[j]*256 + off);
        #pragma unroll
        for (int j = 0; j < 4; ++j){
            a0 += bf_lo(v[j].x); a1 += bf_hi(v[j].x);
            a2 += bf_lo(v[j].y); a3 += bf_hi(v[j].y);
        }
    }
    for (; e < e1; ++e){
        int s0 = csr_src[e];
        uint2 v0 = *(const uint2*)(xI + (size_t)s0*256 + off);
        a0 += bf_lo(v0.x); a1 += bf_hi(v0.x);
        a2 += bf_lo(v0.y); a3 += bf_hi(v0.y);
    }
    uint2 o;
    o.x = (uint)f2bf(a0) | ((uint)f2bf(a1) << 16);
    o.y = (uint)f2bf(a2) | ((uint)f2bf(a3) << 16);
    int b = l >> 4, c4 = (l & 15)*4;
    *(uint2*)(aggx + ((size_t)b*NN + d)*64 + c4) = o;
}

// ---------------- GRU layer (MFMA, fused weights); last layer fuses attention ----------------
__global__ __launch_bounds__(256) void k_gru(const ushort* __restrict__ xsrc, const ushort* __restrict__ aggx,
                                             const ushort* __restrict__ wfb, const ushort* __restrict__ whhb,
                                             const float* __restrict__ bih, const float* __restrict__ bhh,
                                             ushort* __restrict__ xIout,
                                             const ushort* __restrict__ x0I,
                                             const ushort* __restrict__ aiwb, const float* __restrict__ aib,
                                             const ushort* __restrict__ ajwb, const float* __restrict__ ajb,
                                             float* __restrict__ pooled, int last){
    __shared__ __align__(16) ushort sA[64*136];   // cols 0..63: agg_x ; cols 64..127: x (bf16)
    const int tx = threadIdx.x;
    const int l  = tx & 63, li = l & 15, q = l >> 4;
    const int w  = __builtin_amdgcn_readfirstlane(tx >> 6);
    const int row0i = blockIdx.x * 64;
    const size_t row0 = (size_t)row0i;

    // stage agg (flat rows) and x (interleaved records)
    #pragma unroll
    for (int it = 0; it < 2; ++it){
        int idx = it*256 + tx;                    // 0..511
        int r = idx >> 3, g = idx & 7;
        uint4 va = *(const uint4*)(aggx + (row0 + r)*64 + g*8);
        *(uint4*)(&sA[r*136 + g*8]) = va;
        int flat = row0i + r;
        int n = flat % NN, b = flat / NN;
        uint4 vx = *(const uint4*)(xsrc + ((size_t)n*4 + b)*64 + g*8);
        *(uint4*)(&sA[r*136 + 64 + g*8]) = vx;
    }
    __syncthreads();

    const int n0 = 16*w;
    f32x4 Cr[4], Cz[4], Cxn[4], Chn[4];
    #pragma unroll
    for (int m = 0; m < 4; ++m){
        Cr[m]=(f32x4){0.f,0.f,0.f,0.f}; Cz[m]=(f32x4){0.f,0.f,0.f,0.f};
        Cxn[m]=(f32x4){0.f,0.f,0.f,0.f}; Chn[m]=(f32x4){0.f,0.f,0.f,0.f};
    }
    bf16x8 Bxn[2], Bhn[2];
    #pragma unroll
    for (int ks = 0; ks < 2; ++ks){
        Bxn[ks] = ldfrag(wfb  + (size_t)(128 + n0 + li)*64 + ks*32 + q*8);
        Bhn[ks] = ldfrag(whhb + (size_t)(128 + n0 + li)*64 + ks*32 + q*8);
    }
    #pragma unroll
    for (int ks = 0; ks < 4; ++ks){
        const ushort* wb = (ks < 2) ? wfb : whhb;
        int kb = (ks & 1)*32;
        bf16x8 Br = ldfrag(wb + (size_t)(n0 + li)*64 + kb + q*8);
        bf16x8 Bz = ldfrag(wb + (size_t)(64 + n0 + li)*64 + kb + q*8);
        #pragma unroll
        for (int m = 0; m < 4; ++m){
            bf16x8 A = ldfrag(&sA[(m*16 + li)*136 + ks*32 + q*8]);
            Cr[m] = MFMA(A, Br, Cr[m]);
            Cz[m] = MFMA(A, Bz, Cz[m]);
            if (ks < 2) Cxn[m] = MFMA(A, Bxn[ks], Cxn[m]);
            else        Chn[m] = MFMA(A, Bhn[ks-2], Chn[m]);
        }
    }

    const int c = n0 + li;
    const float br_ = bih[c]     + bhh[c];
    const float bz_ = bih[64+c]  + bhh[64+c];
    const float bn_ = bih[128+c];
    const float bh_ = bhh[128+c];
    ushort xnew[4][4];
    #pragma unroll
    for (int m = 0; m < 4; ++m){
        #pragma unroll
        for (int rg = 0; rg < 4; ++rg){
            int rl = m*16 + q*4 + rg;
            float r = sigm(Cr[m][rg] + br_);
            float z = sigm(Cz[m][rg] + bz_);
            float n = tanh_f(Cxn[m][rg] + bn_ + r*(Chn[m][rg] + bh_));
            float xo = bf_lo((uint)sA[rl*136 + 64 + c]);
            xnew[m][rg] = f2bf((1.f - z)*n + z*xo);
        }
    }
    __syncthreads();                   // all waves done reading sA
    #pragma unroll
    for (int m = 0; m < 4; ++m){
        #pragma unroll
        for (int rg = 0; rg < 4; ++rg){
            int rl = m*16 + q*4 + rg;
            sA[rl*136 + c] = xnew[m][rg];          // x' into cols 0..63
        }
    }

    if (!last){
        __syncthreads();
        // interleaved bf16 dump for next layer
        #pragma unroll
        for (int it = 0; it < 2; ++it){
            int idx = it*256 + tx;               // 0..511
            int r = idx >> 3, g = idx & 7;
            int flat = row0i + r;
            int n = flat % NN, b = flat / NN;
            uint4 v = *(const uint4*)(&sA[r*136 + g*8]);
            *(uint4*)(xIout + ((size_t)n*4 + b)*64 + g*8) = v;
        }
        return;
    }

    // ---- fused attention: cat = [x' | x0] ----
    #pragma unroll
    for (int it = 0; it < 2; ++it){
        int idx = it*256 + tx;
        int r = idx >> 3, g = idx & 7;
        int flat = row0i + r;
        int n = flat % NN, b = flat / NN;
        uint4 v = *(const uint4*)(x0I + ((size_t)n*4 + b)*64 + g*8);
        *(uint4*)(&sA[r*136 + 64 + g*8]) = v;
    }
    __syncthreads();

    const int nb0 = 32*w;
    f32x4 Ai[2][4], Aj[2][4];
    #pragma unroll
    for (int t = 0; t < 2; ++t)
        #pragma unroll
        for (int m = 0; m < 4; ++m){ Ai[t][m]=(f32x4){0.f,0.f,0.f,0.f}; Aj[t][m]=(f32x4){0.f,0.f,0.f,0.f}; }

    #pragma unroll
    for (int ks = 0; ks < 4; ++ks){
        bf16x8 Bi[2], Bj[2];
        #pragma unroll
        for (int t = 0; t < 2; ++t){
            Bi[t] = ldfrag(aiwb + (size_t)(nb0 + 16*t + li)*128 + ks*32 + q*8);
            Bj[t] = ldfrag(ajwb + (size_t)(nb0 + 16*t + li)*128 + ks*32 + q*8);
        }
        #pragma unroll
        for (int m = 0; m < 4; ++m){
            bf16x8 A = ldfrag(&sA[(m*16 + li)*136 + ks*32 + q*8]);
            #pragma unroll
            for (int t = 0; t < 2; ++t){
                Ai[t][m] = MFMA(A, Bi[t], Ai[t][m]);
                Aj[t][m] = MFMA(A, Bj[t], Aj[t][m]);
            }
        }
    }

    const int b0 = row0i / NN, b1 = (row0i + 63) / NN;
    const int thr = (b0 + 1) * NN;
    #pragma unroll
    for (int t = 0; t < 2; ++t){
        int cc = nb0 + 16*t + li;
        float bia = aib[cc], bja = ajb[cc];
        float vsa = 0.f, vsb = 0.f;
        #pragma unroll
        for (int m = 0; m < 4; ++m){
            #pragma unroll
            for (int rg = 0; rg < 4; ++rg){
                int rl = m*16 + q*4 + rg;
                float s = sigm(Ai[t][m][rg] + bia);
                float a = Aj[t][m][rg] + bja;
                a = a > 0.f ? a : 0.f;
                float v = s*a;
                if (row0i + rl >= thr) vsb += v; else vsa += v;
            }
        }
        vsa += __shfl_xor(vsa, 16);
        vsa += __shfl_xor(vsa, 32);
        if (l < 16) atomicAdd(&pooled[b0*128 + nb0 + 16*t + l], vsa);
        if (b1 != b0){
            vsb += __shfl_xor(vsb, 16);
            vsb += __shfl_xor(vsb, 32);
            if (l < 16) atomicAdd(&pooled[b1*128 + nb0 + 16*t + l], vsb);
        }
    }
}

// ---------------- final MLP + critic ----------------
__global__ void k_final(const float* __restrict__ pooled, const float* __restrict__ mw,
                        const float* __restrict__ mb, const float* __restrict__ cw,
                        const float* __restrict__ cb, float* __restrict__ out){
    __shared__ float red[256];
    int t = threadIdx.x;
    for (int b = 0; b < NB; ++b){
        float acc = mb[t];
        #pragma unroll 8
        for (int k = 0; k < 128; ++k){
            float p = pooled[b*128 + k];
            p = p > 0.f ? p : 0.f;
            acc = fmaf(p, mw[t*128 + k], acc);
        }
        float st = acc > 0.f ? acc : 0.f;
        red[t] = st * cw[t];
        __syncthreads();
        for (int off = 128; off > 0; off >>= 1){
            if (t < off) red[t] += red[t + off];
            __syncthreads();
        }
        if (t == 0) out[b] = red[0] + cb[0];
        __syncthreads();
    }
}

extern "C" void kernel_launch(void* const* d_in, const int* in_sizes, int n_in,
                              void* d_out, int out_size, void* d_ws, size_t ws_size,
                              hipStream_t stream) {
    const float* cov   = (const float*)d_in[0];
    const float* nodes = (const float*)d_in[1];
    const int*   edges = (const int*)d_in[2];
    const int*   c2l   = (const int*)d_in[3];
    const float* ggc   = (const float*)d_in[4];
    const float* wih   = (const float*)d_in[5];
    const float* whh   = (const float*)d_in[6];
    const float* bih   = (const float*)d_in[7];
    const float* bhh   = (const float*)d_in[8];
    const float* aiw   = (const float*)d_in[9];
    const float* aib   = (const float*)d_in[10];
    const float* ajw   = (const float*)d_in[11];
    const float* ajb   = (const float*)d_in[12];
    const float* mlpw  = (const float*)d_in[13];
    const float* mlpb  = (const float*)d_in[14];
    const float* cw    = (const float*)d_in[15];
    const float* cb    = (const float*)d_in[16];
    float* out = (float*)d_out;

    const size_t XSZ = (size_t)BN * 64;          // 12.8M elements
    float* ws = (float*)d_ws;
    float* pooled = ws;                          // 512 floats
    ushort* xI    = (ushort*)(pooled + 512);     // bf16 interleaved state [n][b][64]
    ushort* x0I   = xI + XSZ;
    ushort* aggx  = x0I + XSZ;                   // bf16 agg, [b*NN+n][64]
    ushort* whhb  = aggx + XSZ;                  // 12288
    ushort* aiwb  = whhb + 12288;                // 16384
    ushort* ajwb  = aiwb + 16384;                // 16384
    ushort* wfb   = ajwb + 16384;                // 5*12288 fused ih weights
    int* cnt       = (int*)(wfb + 61440);
    int* tmp       = cnt + NN;
    int* bsum      = tmp + NN;
    int* boff      = bsum + 256;
    int* row_start = boff + 256;
    int* cursor    = row_start + (NN + 1);
    int* csr_src   = cursor + NN;

    hipMemsetAsync(cnt, 0, (size_t)NN*sizeof(int), stream);
    hipMemsetAsync(pooled, 0, 512*sizeof(float), stream);

    k_prep<<<416, 256, 0, stream>>>(wih, whh, aiw, ajw, ggc, whhb, aiwb, ajwb, wfb);

    k_hist<<<(NE + 255)/256, 256, 0, stream>>>(edges, cnt);
    k_scan1<<<SCAN_NBLK, 256, 0, stream>>>(cnt, tmp, bsum);
    k_scan2<<<1, 256, 0, stream>>>(bsum, boff);
    k_scan3<<<SCAN_NBLK, 256, 0, stream>>>(tmp, boff, row_start, cursor);
    k_fillcsr<<<(NE + 255)/256, 256, 0, stream>>>(edges, cursor, csr_src);

    k_x0<<<(BN*16)/256, 256, 0, stream>>>(nodes, x0I);
    k_cov<<<(NB*NL + 255)/256, 256, 0, stream>>>(cov, c2l, x0I);

    for (int i = 0; i < NLAY; ++i){
        const ushort* gsrc = (i == 0) ? x0I : xI;
        int last = (i == NLAY - 1);
        k_agg<<<NN/4, 256, 0, stream>>>(gsrc, row_start, csr_src, aggx);
        k_gru<<<NTILES, 256, 0, stream>>>(gsrc, aggx, wfb + (size_t)i*12288, whhb,
                                          bih, bhh, xI, x0I,
                                          aiwb, aib, ajwb, ajb, pooled, last);
    }

    k_final<<<1, 256, 0, stream>>>(pooled, mlpw, mlpb, cw, cb, out);
    (void)in_sizes; (void)n_in; (void)out_size; (void)ws_size;
}

// Round 6
// 721.457 us; speedup vs baseline: 2.5422x; 1.0044x over previous
//
#include <hip/hip_runtime.h>
#include <math.h>

#define NN 50000
#define NF 63
#define NE 800000
#define NL 10000
#define NB 4
#define NLAY 5
#define BN (NB*NN)                 // 200000 rows
#define NTILES (BN/64)             // 3125
#define SCAN_NBLK ((NN+255)/256)   // 196

using f32x4  = __attribute__((ext_vector_type(4))) float;
using bf16x8 = __attribute__((ext_vector_type(8))) __bf16;

__device__ __forceinline__ float frcp(float x){ return __builtin_amdgcn_rcpf(x); }
__device__ __forceinline__ float sigm(float v){ return frcp(1.f + __expf(-v)); }
__device__ __forceinline__ float tanh_f(float v){ return fmaf(-2.f, frcp(__expf(2.f*v) + 1.f), 1.f); }

__device__ __forceinline__ ushort f2bf(float f){
    uint u = __builtin_bit_cast(uint, f);
    u += 0x7fffu + ((u >> 16) & 1u);
    return (ushort)(u >> 16);
}
__device__ __forceinline__ float bf_lo(uint v){ return __builtin_bit_cast(float, v << 16); }
__device__ __forceinline__ float bf_hi(uint v){ return __builtin_bit_cast(float, v & 0xffff0000u); }

__device__ __forceinline__ bf16x8 ldfrag(const ushort* p){
    uint4 v = *(const uint4*)p;
    return __builtin_bit_cast(bf16x8, v);
}
__device__ __forceinline__ f32x4 MFMA(bf16x8 a, bf16x8 b, f32x4 c){
    return __builtin_amdgcn_mfma_f32_16x16x32_bf16(a, b, c, 0, 0, 0);
}

// ---------------- CSR build ----------------
__global__ void k_hist(const int* __restrict__ edges, int* __restrict__ cnt){
    int e = blockIdx.x*256 + threadIdx.x;
    if (e < NE) atomicAdd(&cnt[edges[NE + e]], 1);
}

__global__ void k_scan1(const int* __restrict__ cnt, int* __restrict__ tmp, int* __restrict__ bsum){
    __shared__ int sh[256];
    int tx = threadIdx.x, i = blockIdx.x*256 + tx;
    int v = (i < NN) ? cnt[i] : 0;
    sh[tx] = v; __syncthreads();
    for (int off = 1; off < 256; off <<= 1){
        int u = (tx >= off) ? sh[tx-off] : 0;
        __syncthreads();
        sh[tx] += u;
        __syncthreads();
    }
    int incl = sh[tx];
    if (i < NN) tmp[i] = incl - v;
    if (tx == 255) bsum[blockIdx.x] = incl;
}

__global__ void k_scan2(const int* __restrict__ bsum, int* __restrict__ boff){
    __shared__ int sh[256];
    int tx = threadIdx.x;
    int v = (tx < SCAN_NBLK) ? bsum[tx] : 0;
    sh[tx] = v; __syncthreads();
    for (int off = 1; off < 256; off <<= 1){
        int u = (tx >= off) ? sh[tx-off] : 0;
        __syncthreads();
        sh[tx] += u;
        __syncthreads();
    }
    boff[tx] = sh[tx] - v;
}

__global__ void k_scan3(const int* __restrict__ tmp, const int* __restrict__ boff,
                        int* __restrict__ row_start, int* __restrict__ cursor){
    int i = blockIdx.x*256 + threadIdx.x;
    if (i < NN){
        int rs = tmp[i] + boff[blockIdx.x];
        row_start[i] = rs;
        cursor[i] = rs;
    }
    if (i == 0) row_start[NN] = NE;
}

__global__ void k_fillcsr(const int* __restrict__ edges, int* __restrict__ cursor, int* __restrict__ csr_src){
    int e = blockIdx.x*256 + threadIdx.x;
    if (e < NE){
        int d = edges[NE + e];
        int pos = atomicAdd(&cursor[d], 1);
        csr_src[pos] = edges[e];
    }
}

// ---------------- weight prep ----------------
// wfb[i][n][k] = sum_c ggc[i][k][c] * wih[n][c]   (agg_x @ wfb^T == (agg_x@W_i) @ wih^T)
__global__ void k_prep(const float* __restrict__ wih, const float* __restrict__ whh,
                       const float* __restrict__ aiw, const float* __restrict__ ajw,
                       const float* __restrict__ ggc,
                       ushort* __restrict__ whhb, ushort* __restrict__ aiwb,
                       ushort* __restrict__ ajwb, ushort* __restrict__ wfb){
    int i = blockIdx.x*256 + threadIdx.x;       // 0..106495
    if (i < 12288)        whhb[i]        = f2bf(whh[i]);
    else if (i < 28672)   aiwb[i-12288]  = f2bf(aiw[i-12288]);
    else if (i < 45056)   ajwb[i-28672]  = f2bf(ajw[i-28672]);
    else {
        int t = i - 45056;                       // 0..61439
        int lay = t / 12288;
        int rem = t % 12288;
        int n = rem >> 6, k = rem & 63;
        const float* W  = ggc + lay*4096 + k*64;
        const float* wr = wih + n*64;
        float s = 0.f;
        #pragma unroll 8
        for (int c = 0; c < 64; ++c) s = fmaf(W[c], wr[c], s);
        wfb[t] = f2bf(s);
    }
}

// ---------------- x0 build: interleaved x0I + batch-invariant compact x0C ----------------
__global__ void k_x0(const float* __restrict__ nodes, ushort* __restrict__ x0I,
                     ushort* __restrict__ x0C){
    int f = blockIdx.x*256 + threadIdx.x;       // 8B group index, BN*16 total
    int row = f >> 4, c4 = f & 15;
    int n = row % NN, b = row / NN;
    float v[4];
    #pragma unroll
    for (int i = 0; i < 4; ++i){
        int c = c4*4 + i;
        v[i] = (c < NF) ? nodes[(size_t)n*NF + c] : 0.f;
    }
    uint2 pk;
    pk.x = (uint)f2bf(v[0]) | ((uint)f2bf(v[1]) << 16);
    pk.y = (uint)f2bf(v[2]) | ((uint)f2bf(v[3]) << 16);
    *(uint2*)(x0I + ((size_t)n*4 + b)*64 + c4*4) = pk;
    if (b == 0) *(uint2*)(x0C + (size_t)n*64 + c4*4) = pk;   // col63 stays 0 (v[3]=0 for c4=15)
}

__global__ void k_cov(const float* __restrict__ cov, const int* __restrict__ c2l,
                      ushort* __restrict__ x0I, ushort* __restrict__ covB){
    int i = blockIdx.x*256 + threadIdx.x;
    if (i < NB*NL){
        int b = i / NL, j = i % NL;
        int nd = c2l[j];
        ushort vb = f2bf(cov[i]);
        x0I[((size_t)nd*4 + b)*64 + 63] = vb;
        covB[(size_t)nd*4 + b] = vb;
    }
}

// ---------------- layer-0 agg: batch-invariant gather (128B + 8B per edge) ----------------
__global__ __launch_bounds__(256) void k_agg0(const ushort* __restrict__ x0C,
                                              const ushort* __restrict__ covB,
                                              const int* __restrict__ row_start,
                                              const int* __restrict__ csr_src,
                                              ushort* __restrict__ aggx){
    int tx = threadIdx.x, l = tx & 63, w = tx >> 6;
    int d = __builtin_amdgcn_readfirstlane(blockIdx.x*4 + w);
    int h = l >> 5, t = l & 31;                 // half-wave per edge; lane t covers cols 2t,2t+1
    int e0 = row_start[d], e1 = row_start[d+1];
    float a0 = 0.f, a1 = 0.f, c = 0.f;
    int e = e0 + h;
    for (; e + 6 < e1; e += 8){
        int s0 = csr_src[e], s1 = csr_src[e+2], s2 = csr_src[e+4], s3 = csr_src[e+6];
        uint v0 = *(const uint*)(x0C + (size_t)s0*64 + t*2);
        uint v1 = *(const uint*)(x0C + (size_t)s1*64 + t*2);
        uint v2 = *(const uint*)(x0C + (size_t)s2*64 + t*2);
        uint v3 = *(const uint*)(x0C + (size_t)s3*64 + t*2);
        a0 += bf_lo(v0)+bf_lo(v1)+bf_lo(v2)+bf_lo(v3);
        a1 += bf_hi(v0)+bf_hi(v1)+bf_hi(v2)+bf_hi(v3);
        if (t < 4){
            c += bf_lo((uint)covB[(size_t)s0*4 + t]) + bf_lo((uint)covB[(size_t)s1*4 + t])
               + bf_lo((uint)covB[(size_t)s2*4 + t]) + bf_lo((uint)covB[(size_t)s3*4 + t]);
        }
    }
    for (; e < e1; e += 2){
        int s0 = csr_src[e];
        uint v0 = *(const uint*)(x0C + (size_t)s0*64 + t*2);
        a0 += bf_lo(v0); a1 += bf_hi(v0);
        if (t < 4) c += bf_lo((uint)covB[(size_t)s0*4 + t]);
    }
    a0 += __shfl_xor(a0, 32);
    a1 += __shfl_xor(a1, 32);
    c  += __shfl_xor(c, 32);
    float cb0 = __shfl(c, 0), cb1 = __shfl(c, 1), cb2 = __shfl(c, 2), cb3 = __shfl(c, 3);
    if (h == 0){
        uint pk = (uint)f2bf(a0) | ((uint)f2bf(a1) << 16);
        float cb[4] = {cb0, cb1, cb2, cb3};
        #pragma unroll
        for (int b = 0; b < 4; ++b){
            uint o = pk;
            if (t == 31) o = (o & 0xffffu) | ((uint)f2bf(cb[b]) << 16);   // col63 = cov agg
            *(uint*)(aggx + ((size_t)b*NN + d)*64 + t*2) = o;
        }
    }
}

// ---------------- generic agg: gather-sum of full records ----------------
__global__ __launch_bounds__(256) void k_agg(const ushort* __restrict__ xI,
                                             const int* __restrict__ row_start,
                                             const int* __restrict__ csr_src,
                                             ushort* __restrict__ aggx){
    int tx = threadIdx.x, l = tx & 63, w = tx >> 6;
    int d = __builtin_amdgcn_readfirstlane(blockIdx.x*4 + w);
    const uint off = (uint)(l*4);       // 8 B per lane
    int e0 = row_start[d], e1 = row_start[d+1];
    float a0=0.f,a1=0.f,a2=0.f,a3=0.f;
    int e = e0;
    for (; e + 7 < e1; e += 8){
        int s[8];
        #pragma unroll
        for (int j = 0; j < 8; ++j) s[j] = csr_src[e+j];
        uint2 v[8];
        #pragma unroll
        for (int j = 0; j < 8; ++j) v[j] = *(const uint2*)(xI + (size_t)s[j]*256 + off);
        #pragma unroll
        for (int j = 0; j < 8; ++j){
            a0 += bf_lo(v[j].x); a1 += bf_hi(v[j].x);
            a2 += bf_lo(v[j].y); a3 += bf_hi(v[j].y);
        }
    }
    for (; e + 3 < e1; e += 4){
        int s[4];
        #pragma unroll
        for (int j = 0; j < 4; ++j) s[j] = csr_src[e+j];
        uint2 v[4];
        #pragma unroll
        for (int j = 0; j < 4; ++j) v[j] = *(const uint2*)(xI + (size_t)s[j]*256 + off);
        #pragma unroll
        for (int j = 0; j < 4; ++j){
            a0 += bf_lo(v[j].x); a1 += bf_hi(v[j].x);
            a2 += bf_lo(v[j].y); a3 += bf_hi(v[j].y);
        }
    }
    for (; e < e1; ++e){
        int s0 = csr_src[e];
        uint2 v0 = *(const uint2*)(xI + (size_t)s0*256 + off);
        a0 += bf_lo(v0.x); a1 += bf_hi(v0.x);
        a2 += bf_lo(v0.y); a3 += bf_hi(v0.y);
    }
    uint2 o;
    o.x = (uint)f2bf(a0) | ((uint)f2bf(a1) << 16);
    o.y = (uint)f2bf(a2) | ((uint)f2bf(a3) << 16);
    int b = l >> 4, c4 = (l & 15)*4;
    *(uint2*)(aggx + ((size_t)b*NN + d)*64 + c4) = o;
}

// ---------------- GRU layer (MFMA, fused weights); LAST variant fuses attention ----------------
template<bool LAST>
__global__ __launch_bounds__(256) void k_gru_t(const ushort* __restrict__ xsrc, const ushort* __restrict__ aggx,
                                               const ushort* __restrict__ wfb, const ushort* __restrict__ whhb,
                                               const float* __restrict__ bih, const float* __restrict__ bhh,
                                               ushort* __restrict__ xIout,
                                               const ushort* __restrict__ x0I,
                                               const ushort* __restrict__ aiwb, const float* __restrict__ aib,
                                               const ushort* __restrict__ ajwb, const float* __restrict__ ajb,
                                               float* __restrict__ pooled){
    __shared__ __align__(16) ushort sA[64*136];   // cols 0..63: agg_x ; cols 64..127: x (bf16)
    const int tx = threadIdx.x;
    const int l  = tx & 63, li = l & 15, q = l >> 4;
    const int w  = __builtin_amdgcn_readfirstlane(tx >> 6);
    const int row0i = blockIdx.x * 64;
    const size_t row0 = (size_t)row0i;

    // prefetch x0 tile (att input) at kernel top to hide its latency behind the GRU
    uint4 p0[2];
    if (LAST){
        #pragma unroll
        for (int it = 0; it < 2; ++it){
            int idx = it*256 + tx;
            int r = idx >> 3, g = idx & 7;
            int flat = row0i + r;
            int n = flat % NN, b = flat / NN;
            p0[it] = *(const uint4*)(x0I + ((size_t)n*4 + b)*64 + g*8);
        }
    }

    // stage agg (flat rows) and x (interleaved records)
    #pragma unroll
    for (int it = 0; it < 2; ++it){
        int idx = it*256 + tx;                    // 0..511
        int r = idx >> 3, g = idx & 7;
        uint4 va = *(const uint4*)(aggx + (row0 + r)*64 + g*8);
        *(uint4*)(&sA[r*136 + g*8]) = va;
        int flat = row0i + r;
        int n = flat % NN, b = flat / NN;
        uint4 vx = *(const uint4*)(xsrc + ((size_t)n*4 + b)*64 + g*8);
        *(uint4*)(&sA[r*136 + 64 + g*8]) = vx;
    }
    __syncthreads();

    const int n0 = 16*w;
    f32x4 Cr[4], Cz[4], Cxn[4], Chn[4];
    #pragma unroll
    for (int m = 0; m < 4; ++m){
        Cr[m]=(f32x4){0.f,0.f,0.f,0.f}; Cz[m]=(f32x4){0.f,0.f,0.f,0.f};
        Cxn[m]=(f32x4){0.f,0.f,0.f,0.f}; Chn[m]=(f32x4){0.f,0.f,0.f,0.f};
    }
    bf16x8 Bxn[2], Bhn[2];
    #pragma unroll
    for (int ks = 0; ks < 2; ++ks){
        Bxn[ks] = ldfrag(wfb  + (size_t)(128 + n0 + li)*64 + ks*32 + q*8);
        Bhn[ks] = ldfrag(whhb + (size_t)(128 + n0 + li)*64 + ks*32 + q*8);
    }
    #pragma unroll
    for (int ks = 0; ks < 4; ++ks){
        const ushort* wb = (ks < 2) ? wfb : whhb;
        int kb = (ks & 1)*32;
        bf16x8 Br = ldfrag(wb + (size_t)(n0 + li)*64 + kb + q*8);
        bf16x8 Bz = ldfrag(wb + (size_t)(64 + n0 + li)*64 + kb + q*8);
        #pragma unroll
        for (int m = 0; m < 4; ++m){
            bf16x8 A = ldfrag(&sA[(m*16 + li)*136 + ks*32 + q*8]);
            Cr[m] = MFMA(A, Br, Cr[m]);
            Cz[m] = MFMA(A, Bz, Cz[m]);
            if (ks < 2) Cxn[m] = MFMA(A, Bxn[ks], Cxn[m]);
            else        Chn[m] = MFMA(A, Bhn[ks-2], Chn[m]);
        }
    }

    const int c = n0 + li;
    const float br_ = bih[c]     + bhh[c];
    const float bz_ = bih[64+c]  + bhh[64+c];
    const float bn_ = bih[128+c];
    const float bh_ = bhh[128+c];
    ushort xnew[4][4];
    #pragma unroll
    for (int m = 0; m < 4; ++m){
        #pragma unroll
        for (int rg = 0; rg < 4; ++rg){
            int rl = m*16 + q*4 + rg;
            float r = sigm(Cr[m][rg] + br_);
            float z = sigm(Cz[m][rg] + bz_);
            float n = tanh_f(Cxn[m][rg] + bn_ + r*(Chn[m][rg] + bh_));
            float xo = bf_lo((uint)sA[rl*136 + 64 + c]);
            xnew[m][rg] = f2bf((1.f - z)*n + z*xo);
        }
    }
    __syncthreads();                   // all waves done reading sA
    #pragma unroll
    for (int m = 0; m < 4; ++m){
        #pragma unroll
        for (int rg = 0; rg < 4; ++rg){
            int rl = m*16 + q*4 + rg;
            sA[rl*136 + c] = xnew[m][rg];          // x' into cols 0..63
        }
    }

    if (!LAST){
        __syncthreads();
        // interleaved bf16 dump for next layer
        #pragma unroll
        for (int it = 0; it < 2; ++it){
            int idx = it*256 + tx;               // 0..511
            int r = idx >> 3, g = idx & 7;
            int flat = row0i + r;
            int n = flat % NN, b = flat / NN;
            uint4 v = *(const uint4*)(&sA[r*136 + g*8]);
            *(uint4*)(xIout + ((size_t)n*4 + b)*64 + g*8) = v;
        }
        return;
    }

    // ---- fused attention: cat = [x' | x0] ----
    #pragma unroll
    for (int it = 0; it < 2; ++it){
        int idx = it*256 + tx;
        int r = idx >> 3, g = idx & 7;
        *(uint4*)(&sA[r*136 + 64 + g*8]) = p0[it];
    }
    __syncthreads();

    const int nb0 = 32*w;
    f32x4 Ai[2][4], Aj[2][4];
    #pragma unroll
    for (int t = 0; t < 2; ++t)
        #pragma unroll
        for (int m = 0; m < 4; ++m){ Ai[t][m]=(f32x4){0.f,0.f,0.f,0.f}; Aj[t][m]=(f32x4){0.f,0.f,0.f,0.f}; }

    #pragma unroll
    for (int ks = 0; ks < 4; ++ks){
        bf16x8 Bi[2], Bj[2];
        #pragma unroll
        for (int t = 0; t < 2; ++t){
            Bi[t] = ldfrag(aiwb + (size_t)(nb0 + 16*t + li)*128 + ks*32 + q*8);
            Bj[t] = ldfrag(ajwb + (size_t)(nb0 + 16*t + li)*128 + ks*32 + q*8);
        }
        #pragma unroll
        for (int m = 0; m < 4; ++m){
            bf16x8 A = ldfrag(&sA[(m*16 + li)*136 + ks*32 + q*8]);
            #pragma unroll
            for (int t = 0; t < 2; ++t){
                Ai[t][m] = MFMA(A, Bi[t], Ai[t][m]);
                Aj[t][m] = MFMA(A, Bj[t], Aj[t][m]);
            }
        }
    }

    const int b0 = row0i / NN, b1 = (row0i + 63) / NN;
    const int thr = (b0 + 1) * NN;
    #pragma unroll
    for (int t = 0; t < 2; ++t){
        int cc = nb0 + 16*t + li;
        float bia = aib[cc], bja = ajb[cc];
        float vsa = 0.f, vsb = 0.f;
        #pragma unroll
        for (int m = 0; m < 4; ++m){
            #pragma unroll
            for (int rg = 0; rg < 4; ++rg){
                int rl = m*16 + q*4 + rg;
                float s = sigm(Ai[t][m][rg] + bia);
                float a = Aj[t][m][rg] + bja;
                a = a > 0.f ? a : 0.f;
                float v = s*a;
                if (row0i + rl >= thr) vsb += v; else vsa += v;
            }
        }
        vsa += __shfl_xor(vsa, 16);
        vsa += __shfl_xor(vsa, 32);
        if (l < 16) atomicAdd(&pooled[b0*128 + nb0 + 16*t + l], vsa);
        if (b1 != b0){
            vsb += __shfl_xor(vsb, 16);
            vsb += __shfl_xor(vsb, 32);
            if (l < 16) atomicAdd(&pooled[b1*128 + nb0 + 16*t + l], vsb);
        }
    }
}

// ---------------- final MLP + critic ----------------
__global__ void k_final(const float* __restrict__ pooled, const float* __restrict__ mw,
                        const float* __restrict__ mb, const float* __restrict__ cw,
                        const float* __restrict__ cb, float* __restrict__ out){
    __shared__ float red[256];
    int t = threadIdx.x;
    for (int b = 0; b < NB; ++b){
        float acc = mb[t];
        #pragma unroll 8
        for (int k = 0; k < 128; ++k){
            float p = pooled[b*128 + k];
            p = p > 0.f ? p : 0.f;
            acc = fmaf(p, mw[t*128 + k], acc);
        }
        float st = acc > 0.f ? acc : 0.f;
        red[t] = st * cw[t];
        __syncthreads();
        for (int off = 128; off > 0; off >>= 1){
            if (t < off) red[t] += red[t + off];
            __syncthreads();
        }
        if (t == 0) out[b] = red[0] + cb[0];
        __syncthreads();
    }
}

extern "C" void kernel_launch(void* const* d_in, const int* in_sizes, int n_in,
                              void* d_out, int out_size, void* d_ws, size_t ws_size,
                              hipStream_t stream) {
    const float* cov   = (const float*)d_in[0];
    const float* nodes = (const float*)d_in[1];
    const int*   edges = (const int*)d_in[2];
    const int*   c2l   = (const int*)d_in[3];
    const float* ggc   = (const float*)d_in[4];
    const float* wih   = (const float*)d_in[5];
    const float* whh   = (const float*)d_in[6];
    const float* bih   = (const float*)d_in[7];
    const float* bhh   = (const float*)d_in[8];
    const float* aiw   = (const float*)d_in[9];
    const float* aib   = (const float*)d_in[10];
    const float* ajw   = (const float*)d_in[11];
    const float* ajb   = (const float*)d_in[12];
    const float* mlpw  = (const float*)d_in[13];
    const float* mlpb  = (const float*)d_in[14];
    const float* cw    = (const float*)d_in[15];
    const float* cb    = (const float*)d_in[16];
    float* out = (float*)d_out;

    const size_t XSZ = (size_t)BN * 64;          // 12.8M elements
    float* ws = (float*)d_ws;
    float* pooled = ws;                          // 512 floats
    ushort* xI    = (ushort*)(pooled + 512);     // bf16 interleaved state [n][b][64]
    ushort* x0I   = xI + XSZ;
    ushort* aggx  = x0I + XSZ;                   // bf16 agg, [b*NN+n][64]
    ushort* x0C   = aggx + XSZ;                  // NN*64 batch-invariant x0 (col63=0)
    ushort* covB  = x0C + (size_t)NN*64;         // NN*4 per-batch cov (bf16)
    ushort* whhb  = covB + (size_t)NN*4;         // 12288
    ushort* aiwb  = whhb + 12288;                // 16384
    ushort* ajwb  = aiwb + 16384;                // 16384
    ushort* wfb   = ajwb + 16384;                // 5*12288 fused ih weights
    int* cnt       = (int*)(wfb + 61440);
    int* tmp       = cnt + NN;
    int* bsum      = tmp + NN;
    int* boff      = bsum + 256;
    int* row_start = boff + 256;
    int* cursor    = row_start + (NN + 1);
    int* csr_src   = cursor + NN;

    hipMemsetAsync(cnt, 0, (size_t)NN*sizeof(int), stream);
    hipMemsetAsync(pooled, 0, 512*sizeof(float), stream);
    hipMemsetAsync(covB, 0, (size_t)NN*4*sizeof(ushort), stream);

    k_prep<<<416, 256, 0, stream>>>(wih, whh, aiw, ajw, ggc, whhb, aiwb, ajwb, wfb);

    k_hist<<<(NE + 255)/256, 256, 0, stream>>>(edges, cnt);
    k_scan1<<<SCAN_NBLK, 256, 0, stream>>>(cnt, tmp, bsum);
    k_scan2<<<1, 256, 0, stream>>>(bsum, boff);
    k_scan3<<<SCAN_NBLK, 256, 0, stream>>>(tmp, boff, row_start, cursor);
    k_fillcsr<<<(NE + 255)/256, 256, 0, stream>>>(edges, cursor, csr_src);

    k_x0<<<(BN*16)/256, 256, 0, stream>>>(nodes, x0I, x0C);
    k_cov<<<(NB*NL + 255)/256, 256, 0, stream>>>(cov, c2l, x0I, covB);

    for (int i = 0; i < NLAY; ++i){
        const ushort* gsrc = (i == 0) ? x0I : xI;
        if (i == 0)
            k_agg0<<<NN/4, 256, 0, stream>>>(x0C, covB, row_start, csr_src, aggx);
        else
            k_agg<<<NN/4, 256, 0, stream>>>(gsrc, row_start, csr_src, aggx);
        if (i < NLAY - 1)
            k_gru_t<false><<<NTILES, 256, 0, stream>>>(gsrc, aggx, wfb + (size_t)i*12288, whhb,
                                                       bih, bhh, xI, x0I,
                                                       aiwb, aib, ajwb, ajb, pooled);
        else
            k_gru_t<true><<<NTILES, 256, 0, stream>>>(gsrc, aggx, wfb + (size_t)i*12288, whhb,
                                                      bih, bhh, xI, x0I,
                                                      aiwb, aib, ajwb, ajb, pooled);
    }

    k_final<<<1, 256, 0, stream>>>(pooled, mlpw, mlpb, cw, cb, out);
    (void)in_sizes; (void)n_in; (void)out_size; (void)ws_size;
}